// Round 1
// baseline (1771.858 us; speedup 1.0000x reference)
//
#include <hip/hip_runtime.h>

#define NN 50000
#define NE 400000
#define NFD 320

typedef short bf16x8 __attribute__((ext_vector_type(8)));
typedef float f32x4 __attribute__((ext_vector_type(4)));

__device__ __forceinline__ unsigned short f2bf(float f){
  unsigned int u = __float_as_uint(f);
  u += 0x7fffu + ((u >> 16) & 1u);
  return (unsigned short)(u >> 16);
}
__device__ __forceinline__ float bflo(unsigned int q){ return __uint_as_float(q << 16); }
__device__ __forceinline__ float bfhi(unsigned int q){ return __uint_as_float(q & 0xffff0000u); }
__device__ __forceinline__ float silu_f(float x){ return x / (1.f + __expf(-x)); }

// Pack weight W [320][kstride] (f32, row-major) into MFMA B-fragment order:
// P[((ct*KS + ks)*64 + lane)*8 + e] = bf16( W[ct*16 + (lane&15)][ks*32 + 8*(lane>>4) + e] )
__global__ void pack_w(const float* __restrict__ W, unsigned short* __restrict__ P,
                       int kstride, int KS){
  int idx = blockIdx.x * 256 + threadIdx.x;
  if (idx >= 20 * KS * 64) return;
  int lane = idx & 63;
  int t  = idx >> 6;
  int ks = t % KS;
  int ct = t / KS;
  const float* src = W + (size_t)(ct*16 + (lane & 15)) * kstride + ks*32 + 8*(lane >> 4);
  unsigned int q[4];
  #pragma unroll
  for (int j = 0; j < 4; j++){
    unsigned int a = f2bf(src[2*j]);
    unsigned int b = f2bf(src[2*j+1]);
    q[j] = a | (b << 16);
  }
  *(uint4*)(P + (size_t)idx * 8) = make_uint4(q[0], q[1], q[2], q[3]);
}

__global__ void extract_last(const float* __restrict__ W, float* __restrict__ out){
  int o = threadIdx.x;           // 320 threads
  out[o] = W[(size_t)o * 641 + 640];
}

// ---------------- edge kernel ----------------
__global__ void __launch_bounds__(512)
edge_kernel(const float* __restrict__ h, const float* __restrict__ coord,
            const int* __restrict__ ei,
            const unsigned short* __restrict__ We1p, const float* __restrict__ we1l,
            const float* __restrict__ be1,
            const unsigned short* __restrict__ We2p, const float* __restrict__ be2,
            const unsigned short* __restrict__ Wc1p, const float* __restrict__ bc1,
            const float* __restrict__ Wc2,
            unsigned short* __restrict__ agg, float* __restrict__ cacc)
{
  __shared__ __align__(16) unsigned short s_in[64*648]; // edge_in bf16 / later m2 [64][328]
  __shared__ __align__(16) unsigned short s_b[64*328];  // m1, later c1
  __shared__ float4 s_cd[64];
  __shared__ int s_row[64];
  __shared__ int s_col[64];

  const int tid  = threadIdx.x;
  const int lane = tid & 63;
  const int wv   = tid >> 6;
  const int e0   = blockIdx.x * 64;

  if (tid < 64){
    int e = e0 + tid;
    int r = ei[e];
    int c = ei[NE + e];
    s_row[tid] = r; s_col[tid] = c;
    float dx = coord[r*3+0] - coord[c*3+0];
    float dy = coord[r*3+1] - coord[c*3+1];
    float dz = coord[r*3+2] - coord[c*3+2];
    float rad = dx*dx + dy*dy + dz*dz;
    float inv = 1.f / (sqrtf(rad) + 1e-8f);
    s_cd[tid] = make_float4(dx*inv, dy*inv, dz*inv, rad);
  }
  __syncthreads();

  // stage h[row] | h[col] as bf16: 64 rows x 160 float4-chunks
  #pragma unroll
  for (int i = 0; i < 20; i++){
    int idx = tid + i*512;
    int r = idx / 160;
    int c = idx - r*160;
    int node = (c < 80) ? s_row[r] : s_col[r];
    int off  = (c < 80) ? c : c - 80;
    float4 v = *(const float4*)(h + (size_t)node*NFD + off*4);
    unsigned int lo = (unsigned int)f2bf(v.x) | ((unsigned int)f2bf(v.y) << 16);
    unsigned int hi = (unsigned int)f2bf(v.z) | ((unsigned int)f2bf(v.w) << 16);
    *(uint2*)(s_in + r*648 + c*4) = make_uint2(lo, hi);
  }
  __syncthreads();

  const int rt = wv & 3;
  const int ch = wv >> 2;
  const int r0 = rt * 16;
  const int arow = r0 + (lane & 15);
  const int kl = 8 * (lane >> 4);
  const int colbase = ch * 160;
  const int rbase = r0 + (lane >> 4)*4;

  f32x4 acc[10];

  // ---- L1: edge_in[64,640] @ We1^T + radial term + bias, silu -> m1 (s_b) ----
  #pragma unroll
  for (int t = 0; t < 10; t++) acc[t] = {0.f,0.f,0.f,0.f};
  for (int ks = 0; ks < 20; ks++){
    bf16x8 a = *(const bf16x8*)(s_in + arow*648 + ks*32 + kl);
    #pragma unroll
    for (int t = 0; t < 10; t++){
      bf16x8 b = *(const bf16x8*)(We1p + ((size_t)((ch*10 + t)*20 + ks)*64 + lane)*8);
      acc[t] = __builtin_amdgcn_mfma_f32_16x16x32_bf16(a, b, acc[t], 0, 0, 0);
    }
  }
  #pragma unroll
  for (int t = 0; t < 10; t++){
    int o = colbase + t*16 + (lane & 15);
    float wl = we1l[o];
    float bb = be1[o];
    #pragma unroll
    for (int r = 0; r < 4; r++){
      float v = silu_f(acc[t][r] + s_cd[rbase + r].w * wl + bb);
      s_b[(rbase + r)*328 + o] = f2bf(v);
    }
  }
  __syncthreads();

  // ---- L2: m2 = silu(m1 @ We2^T + be2) -> s_in region (stride 328) ----
  #pragma unroll
  for (int t = 0; t < 10; t++) acc[t] = {0.f,0.f,0.f,0.f};
  for (int ks = 0; ks < 10; ks++){
    bf16x8 a = *(const bf16x8*)(s_b + arow*328 + ks*32 + kl);
    #pragma unroll
    for (int t = 0; t < 10; t++){
      bf16x8 b = *(const bf16x8*)(We2p + ((size_t)((ch*10 + t)*10 + ks)*64 + lane)*8);
      acc[t] = __builtin_amdgcn_mfma_f32_16x16x32_bf16(a, b, acc[t], 0, 0, 0);
    }
  }
  #pragma unroll
  for (int t = 0; t < 10; t++){
    int o = colbase + t*16 + (lane & 15);
    float bb = be2[o];
    #pragma unroll
    for (int r = 0; r < 4; r++){
      float v = silu_f(acc[t][r] + bb);
      s_in[(rbase + r)*328 + o] = f2bf(v);
    }
  }
  __syncthreads();

  // ---- c1 = silu(m2 @ Wc1^T + bc1) -> s_b ----
  #pragma unroll
  for (int t = 0; t < 10; t++) acc[t] = {0.f,0.f,0.f,0.f};
  for (int ks = 0; ks < 10; ks++){
    bf16x8 a = *(const bf16x8*)(s_in + arow*328 + ks*32 + kl);
    #pragma unroll
    for (int t = 0; t < 10; t++){
      bf16x8 b = *(const bf16x8*)(Wc1p + ((size_t)((ch*10 + t)*10 + ks)*64 + lane)*8);
      acc[t] = __builtin_amdgcn_mfma_f32_16x16x32_bf16(a, b, acc[t], 0, 0, 0);
    }
  }
  #pragma unroll
  for (int t = 0; t < 10; t++){
    int o = colbase + t*16 + (lane & 15);
    float bb = bc1[o];
    #pragma unroll
    for (int r = 0; r < 4; r++){
      float v = silu_f(acc[t][r] + bb);
      s_b[(rbase + r)*328 + o] = f2bf(v);
    }
  }
  __syncthreads();

  // ---- w = c1 . Wc2 (8 threads/edge), coord atomic scatter ----
  {
    int e = tid >> 3;
    int j = tid & 7;
    const float* w8 = Wc2 + j*40;
    float sum = 0.f;
    #pragma unroll
    for (int u = 0; u < 5; u++){
      uint4 q = *(const uint4*)(s_b + e*328 + j*40 + u*8);
      const float* w = w8 + u*8;
      sum += bflo(q.x)*w[0] + bfhi(q.x)*w[1] + bflo(q.y)*w[2] + bfhi(q.y)*w[3]
           + bflo(q.z)*w[4] + bfhi(q.z)*w[5] + bflo(q.w)*w[6] + bfhi(q.w)*w[7];
    }
    sum += __shfl_xor(sum, 1);
    sum += __shfl_xor(sum, 2);
    sum += __shfl_xor(sum, 4);
    if (j == 0){
      float4 cd = s_cd[e];
      float* dst = cacc + (size_t)s_row[e] * 3;
      atomicAdd(dst+0, cd.x*sum);
      atomicAdd(dst+1, cd.y*sum);
      atomicAdd(dst+2, cd.z*sum);
    }
  }

  // ---- scatter m2 (bf16 pairs) into agg with packed bf16 atomics ----
  #pragma unroll
  for (int i = 0; i < 20; i++){
    int idx = tid + i*512;
    int e = idx / 160;
    int c = idx - e*160;
    unsigned int val = *(const unsigned int*)(s_in + e*328 + c*2);
    unsigned short* p = agg + (size_t)s_row[e]*NFD + c*2;
    asm volatile("global_atomic_pk_add_bf16 %0, %1, off" :: "v"(p), "v"(val) : "memory");
  }
}

// ---------------- node kernel ----------------
__global__ void __launch_bounds__(512)
node_kernel(const float* __restrict__ h, const unsigned short* __restrict__ agg,
            const unsigned short* __restrict__ Wn1p, const float* __restrict__ bn1,
            const unsigned short* __restrict__ Wn2p, const float* __restrict__ bn2,
            float* __restrict__ hout)
{
  __shared__ __align__(16) unsigned short s_in[64*648];
  __shared__ __align__(16) unsigned short s_h[64*328];

  const int tid  = threadIdx.x;
  const int lane = tid & 63;
  const int wv   = tid >> 6;
  const int n0   = blockIdx.x * 64;

  // stage [h | agg]: 64 rows x (80 f32x4 + 40 bf16x8) chunks
  #pragma unroll
  for (int i = 0; i < 15; i++){
    int idx = tid + i*512;
    int r = idx / 120;
    int c = idx - r*120;
    int node = n0 + r;
    bool ok = node < NN;
    if (c < 80){
      float4 v = ok ? *(const float4*)(h + (size_t)node*NFD + c*4) : make_float4(0,0,0,0);
      unsigned int lo = (unsigned int)f2bf(v.x) | ((unsigned int)f2bf(v.y) << 16);
      unsigned int hi = (unsigned int)f2bf(v.z) | ((unsigned int)f2bf(v.w) << 16);
      *(uint2*)(s_in + r*648 + c*4) = make_uint2(lo, hi);
    } else {
      int cc = c - 80;
      uint4 v = ok ? *(const uint4*)(agg + (size_t)node*NFD + cc*8) : make_uint4(0,0,0,0);
      *(uint4*)(s_in + r*648 + 320 + cc*8) = v;
    }
  }
  __syncthreads();

  const int rt = wv & 3;
  const int ch = wv >> 2;
  const int r0 = rt * 16;
  const int arow = r0 + (lane & 15);
  const int kl = 8 * (lane >> 4);
  const int colbase = ch * 160;
  const int rbase = r0 + (lane >> 4)*4;

  f32x4 acc[10];

  // ---- n1: node_in[64,640] @ Wn1^T + bn1, silu -> s_h ----
  #pragma unroll
  for (int t = 0; t < 10; t++) acc[t] = {0.f,0.f,0.f,0.f};
  for (int ks = 0; ks < 20; ks++){
    bf16x8 a = *(const bf16x8*)(s_in + arow*648 + ks*32 + kl);
    #pragma unroll
    for (int t = 0; t < 10; t++){
      bf16x8 b = *(const bf16x8*)(Wn1p + ((size_t)((ch*10 + t)*20 + ks)*64 + lane)*8);
      acc[t] = __builtin_amdgcn_mfma_f32_16x16x32_bf16(a, b, acc[t], 0, 0, 0);
    }
  }
  #pragma unroll
  for (int t = 0; t < 10; t++){
    int o = colbase + t*16 + (lane & 15);
    float bb = bn1[o];
    #pragma unroll
    for (int r = 0; r < 4; r++){
      float v = silu_f(acc[t][r] + bb);
      s_h[(rbase + r)*328 + o] = f2bf(v);
    }
  }
  __syncthreads();

  // ---- n2: out = hid @ Wn2^T + bn2 + h (residual) ----
  #pragma unroll
  for (int t = 0; t < 10; t++) acc[t] = {0.f,0.f,0.f,0.f};
  for (int ks = 0; ks < 10; ks++){
    bf16x8 a = *(const bf16x8*)(s_h + arow*328 + ks*32 + kl);
    #pragma unroll
    for (int t = 0; t < 10; t++){
      bf16x8 b = *(const bf16x8*)(Wn2p + ((size_t)((ch*10 + t)*10 + ks)*64 + lane)*8);
      acc[t] = __builtin_amdgcn_mfma_f32_16x16x32_bf16(a, b, acc[t], 0, 0, 0);
    }
  }
  #pragma unroll
  for (int t = 0; t < 10; t++){
    int o = colbase + t*16 + (lane & 15);
    float bb = bn2[o];
    #pragma unroll
    for (int r = 0; r < 4; r++){
      int node = n0 + rbase + r;
      if (node < NN){
        hout[(size_t)node*NFD + o] = h[(size_t)node*NFD + o] + acc[t][r] + bb;
      }
    }
  }
}

__global__ void coord_fin(const float* __restrict__ coord, float* __restrict__ outc){
  int i = blockIdx.x * 256 + threadIdx.x;
  if (i < NN*3) outc[i] += coord[i];
}

extern "C" void kernel_launch(void* const* d_in, const int* in_sizes, int n_in,
                              void* d_out, int out_size, void* d_ws, size_t ws_size,
                              hipStream_t stream){
  const float* h     = (const float*)d_in[0];
  const float* coord = (const float*)d_in[1];
  const int*   ei    = (const int*)d_in[2];
  const float* We1 = (const float*)d_in[3];
  const float* be1 = (const float*)d_in[4];
  const float* We2 = (const float*)d_in[5];
  const float* be2 = (const float*)d_in[6];
  const float* Wn1 = (const float*)d_in[7];
  const float* bn1 = (const float*)d_in[8];
  const float* Wn2 = (const float*)d_in[9];
  const float* bn2 = (const float*)d_in[10];
  const float* Wc1 = (const float*)d_in[11];
  const float* bc1 = (const float*)d_in[12];
  const float* Wc2 = (const float*)d_in[13];

  char* ws = (char*)d_ws;
  unsigned short* We1p = (unsigned short*)(ws);             // 409600 B
  unsigned short* We2p = (unsigned short*)(ws + 409600);    // 204800 B
  unsigned short* Wc1p = (unsigned short*)(ws + 614400);    // 204800 B
  unsigned short* Wn1p = (unsigned short*)(ws + 819200);    // 409600 B
  unsigned short* Wn2p = (unsigned short*)(ws + 1228800);   // 204800 B
  float*          we1l = (float*)(ws + 1433600);            // 1280 B
  unsigned short* agg  = (unsigned short*)(ws + 1434880);   // 32,000,000 B

  float* hout = (float*)d_out;
  float* cout = hout + (size_t)NN * NFD;  // coord output region

  hipMemsetAsync(agg, 0, (size_t)NN * NFD * 2, stream);
  hipMemsetAsync(cout, 0, (size_t)NN * 3 * 4, stream);

  pack_w<<<100, 256, 0, stream>>>(We1, We1p, 641, 20);
  pack_w<<< 50, 256, 0, stream>>>(We2, We2p, 320, 10);
  pack_w<<< 50, 256, 0, stream>>>(Wc1, Wc1p, 320, 10);
  pack_w<<<100, 256, 0, stream>>>(Wn1, Wn1p, 640, 20);
  pack_w<<< 50, 256, 0, stream>>>(Wn2, Wn2p, 320, 10);
  extract_last<<<1, 320, 0, stream>>>(We1, we1l);

  edge_kernel<<<NE/64, 512, 0, stream>>>(h, coord, ei, We1p, we1l, be1,
                                         We2p, be2, Wc1p, bc1, Wc2, agg, cout);
  node_kernel<<<(NN + 63)/64, 512, 0, stream>>>(h, agg, Wn1p, bn1, Wn2p, bn2, hout);
  coord_fin<<<(NN*3 + 255)/256, 256, 0, stream>>>(coord, cout);
}

// Round 2
// 1339.087 us; speedup vs baseline: 1.3232x; 1.3232x over previous
//
#include <hip/hip_runtime.h>

#define NN 50000
#define NE 400000
#define NFD 320

typedef short bf16x8 __attribute__((ext_vector_type(8)));
typedef float f32x4 __attribute__((ext_vector_type(4)));

__device__ __forceinline__ unsigned short f2bf(float f){
  unsigned int u = __float_as_uint(f);
  u += 0x7fffu + ((u >> 16) & 1u);
  return (unsigned short)(u >> 16);
}
__device__ __forceinline__ float bflo(unsigned int q){ return __uint_as_float(q << 16); }
__device__ __forceinline__ float bfhi(unsigned int q){ return __uint_as_float(q & 0xffff0000u); }
__device__ __forceinline__ float silu_f(float x){ return x / (1.f + __expf(-x)); }

// Pack weight W [320][kstride] (f32, row-major) into MFMA B-fragment order:
// P[((ct*KS + ks)*64 + lane)*8 + e] = bf16( W[ct*16 + (lane&15)][ks*32 + 8*(lane>>4) + e] )
__global__ void pack_w(const float* __restrict__ W, unsigned short* __restrict__ P,
                       int kstride, int KS){
  int idx = blockIdx.x * 256 + threadIdx.x;
  if (idx >= 20 * KS * 64) return;
  int lane = idx & 63;
  int t  = idx >> 6;
  int ks = t % KS;
  int ct = t / KS;
  const float* src = W + (size_t)(ct*16 + (lane & 15)) * kstride + ks*32 + 8*(lane >> 4);
  unsigned int q[4];
  #pragma unroll
  for (int j = 0; j < 4; j++){
    unsigned int a = f2bf(src[2*j]);
    unsigned int b = f2bf(src[2*j+1]);
    q[j] = a | (b << 16);
  }
  *(uint4*)(P + (size_t)idx * 8) = make_uint4(q[0], q[1], q[2], q[3]);
}

__global__ void extract_last(const float* __restrict__ W, float* __restrict__ out){
  int o = threadIdx.x;           // 320 threads
  out[o] = W[(size_t)o * 641 + 640];
}

// h (f32) -> bf16, once
__global__ void h2bf(const float* __restrict__ h, unsigned short* __restrict__ hbf){
  int i = blockIdx.x * 256 + threadIdx.x;   // one float4 per thread
  float4 v = *(const float4*)(h + (size_t)i * 4);
  unsigned int lo = (unsigned int)f2bf(v.x) | ((unsigned int)f2bf(v.y) << 16);
  unsigned int hi = (unsigned int)f2bf(v.z) | ((unsigned int)f2bf(v.w) << 16);
  *(uint2*)(hbf + (size_t)i * 4) = make_uint2(lo, hi);
}

__global__ void cinit(const float* __restrict__ coord, float* __restrict__ outc){
  int i = blockIdx.x * 256 + threadIdx.x;
  if (i < NN*3) outc[i] = coord[i];
}

// ---------------- edge kernel: 32 edges/block, 256 threads, ~43KB LDS -> 3 blocks/CU ----
__global__ void __launch_bounds__(256, 3)
edge_kernel(const unsigned short* __restrict__ hbf, const float* __restrict__ coord,
            const int* __restrict__ ei,
            const unsigned short* __restrict__ We1p, const float* __restrict__ we1l,
            const float* __restrict__ be1,
            const unsigned short* __restrict__ We2p, const float* __restrict__ be2,
            const unsigned short* __restrict__ Wc1p, const float* __restrict__ bc1,
            const float* __restrict__ Wc2,
            unsigned short* __restrict__ agg, float* __restrict__ cacc)
{
  __shared__ __align__(16) unsigned short s_x[32*328]; // staged input half / m2
  __shared__ __align__(16) unsigned short s_m[32*328]; // m1 / c1
  __shared__ float4 s_cd[32];
  __shared__ int s_row[32];
  __shared__ int s_col[32];

  const int tid  = threadIdx.x;
  const int lane = tid & 63;
  const int wv   = tid >> 6;     // 0..3
  const int e0   = blockIdx.x * 32;

  if (tid < 32){
    int e = e0 + tid;
    int r = ei[e];
    int c = ei[NE + e];
    s_row[tid] = r; s_col[tid] = c;
    float dx = coord[r*3+0] - coord[c*3+0];
    float dy = coord[r*3+1] - coord[c*3+1];
    float dz = coord[r*3+2] - coord[c*3+2];
    float rad = dx*dx + dy*dy + dz*dz;
    float inv = 1.f / (sqrtf(rad) + 1e-8f);
    s_cd[tid] = make_float4(dx*inv, dy*inv, dz*inv, rad);
  }
  __syncthreads();

  const int rt = wv & 1;
  const int ch = wv >> 1;
  const int r0 = rt * 16;
  const int arow = r0 + (lane & 15);
  const int kl = 8 * (lane >> 4);
  const int colbase = ch * 160;
  const int rbase = r0 + (lane >> 4)*4;

  f32x4 acc[10];
  #pragma unroll
  for (int t = 0; t < 10; t++) acc[t] = {0.f,0.f,0.f,0.f};

  // ---- stage h[row] half (pure bf16 copy: 32 rows x 40 uint4 chunks) ----
  #pragma unroll
  for (int i = 0; i < 5; i++){
    int idx = tid + i*256;
    int r = idx / 40;
    int c = idx - r*40;
    uint4 v = *(const uint4*)(hbf + (size_t)s_row[r]*NFD + c*8);
    *(uint4*)(s_x + r*328 + c*8) = v;
  }
  __syncthreads();

  // ---- L1 half0: ks 0..9 ----
  for (int ks = 0; ks < 10; ks++){
    bf16x8 a = *(const bf16x8*)(s_x + arow*328 + ks*32 + kl);
    #pragma unroll
    for (int t = 0; t < 10; t++){
      bf16x8 b = *(const bf16x8*)(We1p + ((size_t)((ch*10 + t)*20 + ks)*64 + lane)*8);
      acc[t] = __builtin_amdgcn_mfma_f32_16x16x32_bf16(a, b, acc[t], 0, 0, 0);
    }
  }
  __syncthreads();

  // ---- stage h[col] half ----
  #pragma unroll
  for (int i = 0; i < 5; i++){
    int idx = tid + i*256;
    int r = idx / 40;
    int c = idx - r*40;
    uint4 v = *(const uint4*)(hbf + (size_t)s_col[r]*NFD + c*8);
    *(uint4*)(s_x + r*328 + c*8) = v;
  }
  __syncthreads();

  // ---- L1 half1: ks 10..19, + radial/bias epilogue -> m1 in s_m ----
  for (int ks = 0; ks < 10; ks++){
    bf16x8 a = *(const bf16x8*)(s_x + arow*328 + ks*32 + kl);
    #pragma unroll
    for (int t = 0; t < 10; t++){
      bf16x8 b = *(const bf16x8*)(We1p + ((size_t)((ch*10 + t)*20 + 10 + ks)*64 + lane)*8);
      acc[t] = __builtin_amdgcn_mfma_f32_16x16x32_bf16(a, b, acc[t], 0, 0, 0);
    }
  }
  #pragma unroll
  for (int t = 0; t < 10; t++){
    int o = colbase + t*16 + (lane & 15);
    float wl = we1l[o];
    float bb = be1[o];
    #pragma unroll
    for (int r = 0; r < 4; r++){
      float v = silu_f(acc[t][r] + s_cd[rbase + r].w * wl + bb);
      s_m[(rbase + r)*328 + o] = f2bf(v);
    }
  }
  __syncthreads();

  // ---- L2: m2 = silu(m1 @ We2^T + be2) -> s_x ----
  #pragma unroll
  for (int t = 0; t < 10; t++) acc[t] = {0.f,0.f,0.f,0.f};
  for (int ks = 0; ks < 10; ks++){
    bf16x8 a = *(const bf16x8*)(s_m + arow*328 + ks*32 + kl);
    #pragma unroll
    for (int t = 0; t < 10; t++){
      bf16x8 b = *(const bf16x8*)(We2p + ((size_t)((ch*10 + t)*10 + ks)*64 + lane)*8);
      acc[t] = __builtin_amdgcn_mfma_f32_16x16x32_bf16(a, b, acc[t], 0, 0, 0);
    }
  }
  #pragma unroll
  for (int t = 0; t < 10; t++){
    int o = colbase + t*16 + (lane & 15);
    float bb = be2[o];
    #pragma unroll
    for (int r = 0; r < 4; r++){
      float v = silu_f(acc[t][r] + bb);
      s_x[(rbase + r)*328 + o] = f2bf(v);
    }
  }
  __syncthreads();

  // ---- c1 = silu(m2 @ Wc1^T + bc1) -> s_m ----
  #pragma unroll
  for (int t = 0; t < 10; t++) acc[t] = {0.f,0.f,0.f,0.f};
  for (int ks = 0; ks < 10; ks++){
    bf16x8 a = *(const bf16x8*)(s_x + arow*328 + ks*32 + kl);
    #pragma unroll
    for (int t = 0; t < 10; t++){
      bf16x8 b = *(const bf16x8*)(Wc1p + ((size_t)((ch*10 + t)*10 + ks)*64 + lane)*8);
      acc[t] = __builtin_amdgcn_mfma_f32_16x16x32_bf16(a, b, acc[t], 0, 0, 0);
    }
  }
  #pragma unroll
  for (int t = 0; t < 10; t++){
    int o = colbase + t*16 + (lane & 15);
    float bb = bc1[o];
    #pragma unroll
    for (int r = 0; r < 4; r++){
      float v = silu_f(acc[t][r] + bb);
      s_m[(rbase + r)*328 + o] = f2bf(v);
    }
  }
  __syncthreads();

  // ---- w = c1 . Wc2 (8 threads/edge), coord atomic scatter ----
  {
    int e = tid >> 3;            // 0..31
    int j = tid & 7;
    const float* w8 = Wc2 + j*40;
    float sum = 0.f;
    #pragma unroll
    for (int u = 0; u < 5; u++){
      uint4 q = *(const uint4*)(s_m + e*328 + j*40 + u*8);
      const float* w = w8 + u*8;
      sum += bflo(q.x)*w[0] + bfhi(q.x)*w[1] + bflo(q.y)*w[2] + bfhi(q.y)*w[3]
           + bflo(q.z)*w[4] + bfhi(q.z)*w[5] + bflo(q.w)*w[6] + bfhi(q.w)*w[7];
    }
    sum += __shfl_xor(sum, 1);
    sum += __shfl_xor(sum, 2);
    sum += __shfl_xor(sum, 4);
    if (j == 0){
      float4 cd = s_cd[e];
      float* dst = cacc + (size_t)s_row[e] * 3;
      atomicAdd(dst+0, cd.x*sum);
      atomicAdd(dst+1, cd.y*sum);
      atomicAdd(dst+2, cd.z*sum);
    }
  }

  // ---- scatter m2 (bf16 pairs) into agg with packed bf16 atomics ----
  #pragma unroll
  for (int i = 0; i < 20; i++){
    int idx = tid + i*256;
    int e = idx / 160;
    int c = idx - e*160;
    unsigned int val = *(const unsigned int*)(s_x + e*328 + c*2);
    unsigned short* p = agg + (size_t)s_row[e]*NFD + c*2;
    asm volatile("global_atomic_pk_add_bf16 %0, %1, off" :: "v"(p), "v"(val) : "memory");
  }
}

// ---------------- node kernel: 32 nodes/block, 256 threads, 3 blocks/CU ----------------
__global__ void __launch_bounds__(256, 3)
node_kernel(const float* __restrict__ h, const unsigned short* __restrict__ agg,
            const unsigned short* __restrict__ Wn1p, const float* __restrict__ bn1,
            const unsigned short* __restrict__ Wn2p, const float* __restrict__ bn2,
            float* __restrict__ hout)
{
  __shared__ __align__(16) unsigned short s_x[32*328];
  __shared__ __align__(16) unsigned short s_m[32*328];

  const int tid  = threadIdx.x;
  const int lane = tid & 63;
  const int wv   = tid >> 6;
  const int n0   = blockIdx.x * 32;

  const int rt = wv & 1;
  const int ch = wv >> 1;
  const int r0 = rt * 16;
  const int arow = r0 + (lane & 15);
  const int kl = 8 * (lane >> 4);
  const int colbase = ch * 160;
  const int rbase = r0 + (lane >> 4)*4;

  f32x4 acc[10];
  #pragma unroll
  for (int t = 0; t < 10; t++) acc[t] = {0.f,0.f,0.f,0.f};

  // ---- stage h (f32 -> bf16): 32 rows x 80 float4 ----
  #pragma unroll
  for (int i = 0; i < 10; i++){
    int idx = tid + i*256;
    int r = idx / 80;
    int c = idx - r*80;
    int node = n0 + r;
    float4 v = (node < NN) ? *(const float4*)(h + (size_t)node*NFD + c*4)
                           : make_float4(0,0,0,0);
    unsigned int lo = (unsigned int)f2bf(v.x) | ((unsigned int)f2bf(v.y) << 16);
    unsigned int hi = (unsigned int)f2bf(v.z) | ((unsigned int)f2bf(v.w) << 16);
    *(uint2*)(s_x + r*328 + c*4) = make_uint2(lo, hi);
  }
  __syncthreads();

  // ---- n1 half0 (h part): ks 0..9 ----
  for (int ks = 0; ks < 10; ks++){
    bf16x8 a = *(const bf16x8*)(s_x + arow*328 + ks*32 + kl);
    #pragma unroll
    for (int t = 0; t < 10; t++){
      bf16x8 b = *(const bf16x8*)(Wn1p + ((size_t)((ch*10 + t)*20 + ks)*64 + lane)*8);
      acc[t] = __builtin_amdgcn_mfma_f32_16x16x32_bf16(a, b, acc[t], 0, 0, 0);
    }
  }
  __syncthreads();

  // ---- stage agg (bf16 copy): 32 rows x 40 uint4 ----
  #pragma unroll
  for (int i = 0; i < 5; i++){
    int idx = tid + i*256;
    int r = idx / 40;
    int c = idx - r*40;
    int node = n0 + r;
    uint4 v = (node < NN) ? *(const uint4*)(agg + (size_t)node*NFD + c*8)
                          : make_uint4(0,0,0,0);
    *(uint4*)(s_x + r*328 + c*8) = v;
  }
  __syncthreads();

  // ---- n1 half1 (agg part): ks 10..19, silu -> s_m ----
  for (int ks = 0; ks < 10; ks++){
    bf16x8 a = *(const bf16x8*)(s_x + arow*328 + ks*32 + kl);
    #pragma unroll
    for (int t = 0; t < 10; t++){
      bf16x8 b = *(const bf16x8*)(Wn1p + ((size_t)((ch*10 + t)*20 + 10 + ks)*64 + lane)*8);
      acc[t] = __builtin_amdgcn_mfma_f32_16x16x32_bf16(a, b, acc[t], 0, 0, 0);
    }
  }
  #pragma unroll
  for (int t = 0; t < 10; t++){
    int o = colbase + t*16 + (lane & 15);
    float bb = bn1[o];
    #pragma unroll
    for (int r = 0; r < 4; r++){
      float v = silu_f(acc[t][r] + bb);
      s_m[(rbase + r)*328 + o] = f2bf(v);
    }
  }
  __syncthreads();

  // ---- n2: out = hid @ Wn2^T + bn2 + h (residual), straight to global ----
  #pragma unroll
  for (int t = 0; t < 10; t++) acc[t] = {0.f,0.f,0.f,0.f};
  for (int ks = 0; ks < 10; ks++){
    bf16x8 a = *(const bf16x8*)(s_m + arow*328 + ks*32 + kl);
    #pragma unroll
    for (int t = 0; t < 10; t++){
      bf16x8 b = *(const bf16x8*)(Wn2p + ((size_t)((ch*10 + t)*10 + ks)*64 + lane)*8);
      acc[t] = __builtin_amdgcn_mfma_f32_16x16x32_bf16(a, b, acc[t], 0, 0, 0);
    }
  }
  #pragma unroll
  for (int t = 0; t < 10; t++){
    int o = colbase + t*16 + (lane & 15);
    float bb = bn2[o];
    #pragma unroll
    for (int r = 0; r < 4; r++){
      int node = n0 + rbase + r;
      if (node < NN){
        hout[(size_t)node*NFD + o] = h[(size_t)node*NFD + o] + acc[t][r] + bb;
      }
    }
  }
}

extern "C" void kernel_launch(void* const* d_in, const int* in_sizes, int n_in,
                              void* d_out, int out_size, void* d_ws, size_t ws_size,
                              hipStream_t stream){
  const float* h     = (const float*)d_in[0];
  const float* coord = (const float*)d_in[1];
  const int*   ei    = (const int*)d_in[2];
  const float* We1 = (const float*)d_in[3];
  const float* be1 = (const float*)d_in[4];
  const float* We2 = (const float*)d_in[5];
  const float* be2 = (const float*)d_in[6];
  const float* Wn1 = (const float*)d_in[7];
  const float* bn1 = (const float*)d_in[8];
  const float* Wn2 = (const float*)d_in[9];
  const float* bn2 = (const float*)d_in[10];
  const float* Wc1 = (const float*)d_in[11];
  const float* bc1 = (const float*)d_in[12];
  const float* Wc2 = (const float*)d_in[13];

  char* ws = (char*)d_ws;
  unsigned short* We1p = (unsigned short*)(ws);             // 409600 B
  unsigned short* We2p = (unsigned short*)(ws + 409600);    // 204800 B
  unsigned short* Wc1p = (unsigned short*)(ws + 614400);    // 204800 B
  unsigned short* Wn1p = (unsigned short*)(ws + 819200);    // 409600 B
  unsigned short* Wn2p = (unsigned short*)(ws + 1228800);   // 204800 B
  float*          we1l = (float*)(ws + 1433600);            // 1280 B
  unsigned short* agg  = (unsigned short*)(ws + 1434880);   // 32,000,000 B

  float* hout = (float*)d_out;
  float* cout = hout + (size_t)NN * NFD;        // coord output region
  // h_bf lives in the (dead until node_kernel) hout region: 32 MB of 64 MB
  unsigned short* hbf = (unsigned short*)d_out;

  hipMemsetAsync(agg, 0, (size_t)NN * NFD * 2, stream);

  h2bf<<<NN*NFD/4/256, 256, 0, stream>>>(h, hbf);
  cinit<<<(NN*3 + 255)/256, 256, 0, stream>>>(coord, cout);

  pack_w<<<100, 256, 0, stream>>>(We1, We1p, 641, 20);
  pack_w<<< 50, 256, 0, stream>>>(We2, We2p, 320, 10);
  pack_w<<< 50, 256, 0, stream>>>(Wc1, Wc1p, 320, 10);
  pack_w<<<100, 256, 0, stream>>>(Wn1, Wn1p, 640, 20);
  pack_w<<< 50, 256, 0, stream>>>(Wn2, Wn2p, 320, 10);
  extract_last<<<1, 320, 0, stream>>>(We1, we1l);

  edge_kernel<<<NE/32, 256, 0, stream>>>(hbf, coord, ei, We1p, we1l, be1,
                                         We2p, be2, Wc1p, bc1, Wc2, agg, cout);
  node_kernel<<<(NN + 31)/32, 256, 0, stream>>>(h, agg, Wn1p, bn1, Wn2p, bn2, hout);
}